// Round 3
// baseline (325.093 us; speedup 1.0000x reference)
//
#include <hip/hip_runtime.h>
#include <math.h>

#define N_E   32
#define NUP   16
#define N_I   128
#define H_S   512
#define F_LEN 1544      // 3*512 + 2*4
#define N_K   16
#define CH    16
#define CHUNK 97        // ceil(1544/16); last chunk = 89

// workspace layout (float offsets)
#define WS_SH0   0                      // [32][512] ping
#define WS_SH1   16384                  // [32][512] pong
#define WS_DH0   32768                  // [32][32][4] ping
#define WS_DH1   36864                  // [32][32][4] pong
#define WS_ENN   40960                  // [32][128] eN_norm
#define WS_DETS  45056                  // [32]
#define WS_CNT   45088                  // 160 ints: [layer*32+n] for 4 layers, [128] env
#define WS_PART  45568                  // [64 slots][32][512] (4 MB)

// ---------------------------------------------------------------------------
// Init: counters, sh0, dh0, eNn
__global__ void k_init(const float* __restrict__ ep, const float* __restrict__ nuc,
                       float* __restrict__ ws) {
    float* sh  = ws + WS_SH0;
    float* dh  = ws + WS_DH0;
    float* eNn = ws + WS_ENN;
    int*   cnt = (int*)(ws + WS_CNT);
    int t = threadIdx.x;
    if (t < 160) cnt[t] = 0;
    for (int idx = t; idx < N_E * N_I; idx += 256) {
        int j = idx >> 7, m = idx & 127;
        float dx = ep[j*3+0] - nuc[m*3+0];
        float dy = ep[j*3+1] - nuc[m*3+1];
        float dz = ep[j*3+2] - nuc[m*3+2];
        float nr = sqrtf(dx*dx + dy*dy + dz*dz);
        eNn[j*N_I + m] = nr;
        sh[j*H_S + 3*m + 0] = dx;
        sh[j*H_S + 3*m + 1] = dy;
        sh[j*H_S + 3*m + 2] = dz;
        sh[j*H_S + 384 + m] = nr;
    }
    for (int idx = t; idx < N_E * N_E; idx += 256) {
        int a = idx >> 5, b = idx & 31;
        float dx = ep[a*3+0] - ep[b*3+0];
        float dy = ep[a*3+1] - ep[b*3+1];
        float dz = ep[a*3+2] - ep[b*3+2];
        float nr = sqrtf(dx*dx + dy*dy + dz*dz);
        float* d = dh + (a*N_E + b)*4;
        d[0] = dx; d[1] = dy; d[2] = dz; d[3] = nr;
    }
}

// ---------------------------------------------------------------------------
// Fused streaming matvec + last-block reduce.
// Block (n, ch, half): rows f0..f0+flen-1 of V[li,n], cols half*256..+255.
// partial slot = ch*4 + wave, layout partial[slot][n][col].
// Last of the 32 blocks for electron n (device-scope counter) reduces the 64
// slots -> sh_out[n] (tanh+bias+residual) and does the 4x4 dh update.
__global__ __launch_bounds__(256) void k_mv(const float* __restrict__ V,
                                            const float* __restrict__ sh_in,
                                            float* __restrict__ sh_out,
                                            const float* __restrict__ dh_in,
                                            float* __restrict__ dh_out,
                                            const float* __restrict__ bv,
                                            const float* __restrict__ Wm,
                                            const float* __restrict__ cv,
                                            float* __restrict__ partial,
                                            int* __restrict__ cnt, int li) {
    __shared__ float fv[CHUNK];
    int n = blockIdx.x, ch = blockIdx.y, half = blockIdx.z, t = threadIdx.x;
    int f0 = ch * CHUNK;
    int flen = F_LEN - f0; if (flen > CHUNK) flen = CHUNK;

    if (t < flen) {
        int fi = f0 + t;
        float v;
        if (fi < 512) {
            v = sh_in[n*H_S + fi];
        } else if (fi < 1024) {
            float s = 0.f; int o = fi - 512;
            #pragma unroll
            for (int m = 0; m < 16; ++m) s += sh_in[m*H_S + o];
            v = s * 0.0625f;
        } else if (fi < 1536) {
            float s = 0.f; int o = fi - 1024;
            #pragma unroll
            for (int m = 16; m < 32; ++m) s += sh_in[m*H_S + o];
            v = s * 0.0625f;
        } else if (fi < 1540) {
            int i = fi - 1536; float s = 0.f;
            #pragma unroll
            for (int j = 0; j < 16; ++j) s += dh_in[(n*N_E + j)*4 + i];
            v = s * 0.0625f;
        } else {
            int i = fi - 1540; float s = 0.f;
            #pragma unroll
            for (int j = 16; j < 32; ++j) s += dh_in[(n*N_E + j)*4 + i];
            v = s * 0.0625f;
        }
        fv[t] = v;
    }
    __syncthreads();

    int w  = t >> 6;          // wave id 0..3 -> row offset
    int c4 = t & 63;          // float4 column group within the 256-col half
    const float* Vbase = V + ((size_t)(li*N_E + n)*F_LEN + f0)*H_S
                           + half*256 + c4*4;
    float a0 = 0.f, a1 = 0.f, a2 = 0.f, a3 = 0.f;
    #pragma unroll 8
    for (int r = w; r < flen; r += 4) {
        float4 wv = *reinterpret_cast<const float4*>(Vbase + (size_t)r * H_S);
        float fr = fv[r];
        a0 = fmaf(wv.x, fr, a0);
        a1 = fmaf(wv.y, fr, a1);
        a2 = fmaf(wv.z, fr, a2);
        a3 = fmaf(wv.w, fr, a3);
    }
    float4* pp = reinterpret_cast<float4*>(
        partial + (((size_t)(ch*4 + w))*N_E + n)*H_S + half*256) + c4;
    *pp = make_float4(a0, a1, a2, a3);

    // ---- last-block-per-electron tail reduce -------------------------------
    __syncthreads();                       // drains vmcnt: block's stores in L2
    __shared__ int tailFlag;
    if (t == 0) {
        __threadfence();                   // writeback L2 (release)
        int old = atomicAdd(cnt + n, 1);   // device-scope
        tailFlag = (old == 31) ? 1 : 0;
    }
    __syncthreads();
    if (!tailFlag) return;
    __threadfence();                       // invalidate L2 (acquire)

    #pragma unroll
    for (int c = t; c < H_S; c += 256) {
        float s = 0.f;
        #pragma unroll 16
        for (int sl = 0; sl < 64; ++sl)
            s += partial[((size_t)sl*N_E + n)*H_S + c];
        sh_out[n*H_S + c] = tanhf(s + bv[((size_t)li*N_E + n)*H_S + c])
                            + sh_in[n*H_S + c];
    }
    if (t < 128) {
        int j2 = t >> 2, ii = t & 3;
        const float* Wp = Wm + ((((size_t)li*N_E + n)*N_E + j2)*4 + ii)*4;
        const float* dr = dh_in + (n*N_E + j2)*4;
        float acc = Wp[0]*dr[0] + Wp[1]*dr[1] + Wp[2]*dr[2] + Wp[3]*dr[3];
        dh_out[(n*N_E + j2)*4 + ii] =
            tanhf(acc + cv[(((size_t)li*N_E + n)*N_E + j2)*4 + ii]) + dr[ii];
    }
}

// ---------------------------------------------------------------------------
// Fused env + phi + 16x16 determinant + final weighted sum (last-block tail).
// Block b: k = b>>1, spin = b&1. Only diagonal 16x16 blocks of phi needed.
__global__ __launch_bounds__(256) void k_envdet(const float* __restrict__ fw,
                                                const float* __restrict__ fb,
                                                const float* __restrict__ pw,
                                                const float* __restrict__ sw,
                                                const float* __restrict__ omega,
                                                const float* __restrict__ ws,
                                                float* __restrict__ dets,
                                                int* __restrict__ cnt,
                                                float* __restrict__ out) {
    const float* sh  = ws + WS_SH0;   // final sh lands in buf0 after 4 layers
    const float* eNn = ws + WS_ENN;
    int b = blockIdx.x, k = b >> 1, sp = b & 1, base = sp * 16;
    int t = threadIdx.x;
    int i = base + (t >> 4);
    int j = base + (t & 15);

    const float* wv = fw + ((size_t)k*N_E + i)*H_S;
    const float* sv = sh + (size_t)j*H_S;
    float fd = 0.f;
    #pragma unroll 8
    for (int c = 0; c < H_S; c += 4) {
        float4 a  = *reinterpret_cast<const float4*>(wv + c);
        float4 bz = *reinterpret_cast<const float4*>(sv + c);
        fd += a.x*bz.x + a.y*bz.y + a.z*bz.z + a.w*bz.w;
    }
    fd += fb[k*N_E + i];

    const float* pv = pw + ((size_t)k*N_E + i)*N_I;
    const float* sg = sw + ((size_t)k*N_E + i)*N_I;
    const float* rn = eNn + (size_t)j*N_I;
    float env = 0.f;
    #pragma unroll 4
    for (int m = 0; m < N_I; ++m)
        env = fmaf(pv[m], expf(-fabsf(sg[m]) * rn[m]), env);

    __shared__ float phi[16][16];
    phi[t >> 4][t & 15] = fd * env;
    __syncthreads();

    if (t < 64) {
        int lane = t;
        int r = lane & 15;
        float a[16];
        #pragma unroll
        for (int c = 0; c < 16; ++c) a[c] = phi[r][c];
        bool used = (lane >= 16);
        float prod = 1.f;
        int sigma[16];
        #pragma unroll
        for (int p = 0; p < 16; ++p) {
            float v = used ? -1.f : fabsf(a[p]);
            int idx = lane;
            #pragma unroll
            for (int off = 32; off; off >>= 1) {
                float ov = __shfl_xor(v, off);
                int   oi = __shfl_xor(idx, off);
                if (ov > v || (ov == v && oi < idx)) { v = ov; idx = oi; }
            }
            int q = idx;
            float pvt = __shfl(a[p], q);
            prod *= pvt;
            sigma[p] = q;
            float factor = (!used && lane != q && pvt != 0.f) ? (a[p] / pvt) : 0.f;
            #pragma unroll
            for (int c = p; c < 16; ++c) {
                float pr = __shfl(a[c], q);
                a[c] -= factor * pr;
            }
            if (lane == q) used = true;
        }
        if (lane == 0) {
            int inv = 0;
            #pragma unroll
            for (int x = 0; x < 16; ++x)
                #pragma unroll
                for (int y = x + 1; y < 16; ++y) inv += (sigma[x] > sigma[y]) ? 1 : 0;
            dets[b] = prod * ((inv & 1) ? -1.f : 1.f);
        }
    }
    __syncthreads();

    // ---- last-block tail: final weighted sum -------------------------------
    __shared__ int tailFlag;
    if (t == 0) {
        __threadfence();
        int old = atomicAdd(cnt, 1);
        tailFlag = (old == 31) ? 1 : 0;
    }
    __syncthreads();
    if (!tailFlag) return;
    if (t == 0) {
        __threadfence();
        float s = 0.f;
        for (int kk = 0; kk < N_K; ++kk)
            s += omega[kk] * dets[2*kk + 0] * dets[2*kk + 1];
        out[0] = s;
    }
}

// ---------------------------------------------------------------------------
extern "C" void kernel_launch(void* const* d_in, const int* in_sizes, int n_in,
                              void* d_out, int out_size, void* d_ws, size_t ws_size,
                              hipStream_t stream) {
    const float* ep  = (const float*)d_in[0];   // [32,3]
    const float* nuc = (const float*)d_in[1];   // [128,3]
    const float* V   = (const float*)d_in[2];   // [4,32,1544,512]
    const float* bv  = (const float*)d_in[3];   // [4,32,512]
    const float* Wm  = (const float*)d_in[4];   // [4,32,32,4,4]
    const float* cv  = (const float*)d_in[5];   // [4,32,32,4]
    const float* fw  = (const float*)d_in[6];   // [16,32,512]
    const float* fb  = (const float*)d_in[7];   // [16,32]
    const float* pw  = (const float*)d_in[8];   // [16,32,128]
    const float* sw  = (const float*)d_in[9];   // [16,32,128]
    const float* om  = (const float*)d_in[10];  // [16]
    float* out = (float*)d_out;
    float* ws  = (float*)d_ws;

    float* shb[2] = { ws + WS_SH0, ws + WS_SH1 };
    float* dhb[2] = { ws + WS_DH0, ws + WS_DH1 };
    float* partial = ws + WS_PART;
    float* dets    = ws + WS_DETS;
    int*   cnt     = (int*)(ws + WS_CNT);

    k_init<<<dim3(1), dim3(256), 0, stream>>>(ep, nuc, ws);

    // layer sequence quirk: 0, 1, 2, then 2 again; sh/dh ping-pong
    for (int a = 0; a < 4; ++a) {
        int li = (a < 3) ? a : 2;
        k_mv<<<dim3(N_E, CH, 2), dim3(256), 0, stream>>>(
            V, shb[a & 1], shb[(a + 1) & 1], dhb[a & 1], dhb[(a + 1) & 1],
            bv, Wm, cv, partial, cnt + a * N_E, li);
    }
    // after 4 layers, final sh is in buf0
    k_envdet<<<dim3(2 * N_K), dim3(256), 0, stream>>>(
        fw, fb, pw, sw, om, ws, dets, cnt + 128, out);
}

// Round 4
// 130.623 us; speedup vs baseline: 2.4888x; 2.4888x over previous
//
#include <hip/hip_runtime.h>
#include <math.h>

#define N_E   32
#define NUP   16
#define N_I   128
#define H_S   512
#define F_LEN 1544      // 3*512 + 2*4
#define N_K   16

// workspace layout (float offsets)
#define WS_SH0   0                      // [32][512] ping
#define WS_SH1   16384                  // [32][512] pong
#define WS_DH0   32768                  // [32][32][4] ping
#define WS_DH1   36864                  // [32][32][4] pong
#define WS_ENN   40960                  // [32][128] eN_norm
#define WS_DETS  45056                  // [32]

// ---------------------------------------------------------------------------
// Init: eN, eN_norm, sh0, dh0
__global__ void k_init(const float* __restrict__ ep, const float* __restrict__ nuc,
                       float* __restrict__ ws) {
    float* sh  = ws + WS_SH0;
    float* dh  = ws + WS_DH0;
    float* eNn = ws + WS_ENN;
    int t = threadIdx.x;
    for (int idx = t; idx < N_E * N_I; idx += 256) {
        int j = idx >> 7, m = idx & 127;
        float dx = ep[j*3+0] - nuc[m*3+0];
        float dy = ep[j*3+1] - nuc[m*3+1];
        float dz = ep[j*3+2] - nuc[m*3+2];
        float nr = sqrtf(dx*dx + dy*dy + dz*dz);
        eNn[j*N_I + m] = nr;
        sh[j*H_S + 3*m + 0] = dx;
        sh[j*H_S + 3*m + 1] = dy;
        sh[j*H_S + 3*m + 2] = dz;
        sh[j*H_S + 384 + m] = nr;
    }
    for (int idx = t; idx < N_E * N_E; idx += 256) {
        int a = idx >> 5, b = idx & 31;
        float dx = ep[a*3+0] - ep[b*3+0];
        float dy = ep[a*3+1] - ep[b*3+1];
        float dz = ep[a*3+2] - ep[b*3+2];
        float nr = sqrtf(dx*dx + dy*dy + dz*dz);
        float* d = dh + (a*N_E + b)*4;
        d[0] = dx; d[1] = dy; d[2] = dz; d[3] = nr;
    }
}

// ---------------------------------------------------------------------------
// N-split matvec: block (n, cg) owns output columns [cg*64, cg*64+64) of
// electron n and streams ALL F_LEN rows of V[li,n] for that column slice.
// Accumulator is complete per block -> tanh+bias+residual applied here;
// no partial buffer, no reduce kernel, no cross-block communication.
// fv[1544] (incl. g/dg means) rebuilt per block from L2-hot sh/dh.
__global__ __launch_bounds__(512) void k_mv(const float* __restrict__ V,
                                            const float* __restrict__ sh_in,
                                            float* __restrict__ sh_out,
                                            const float* __restrict__ dh_in,
                                            float* __restrict__ dh_out,
                                            const float* __restrict__ bv,
                                            const float* __restrict__ Wm,
                                            const float* __restrict__ cv,
                                            int li) {
    __shared__ float fv[F_LEN];
    __shared__ float part[8][64];
    int n = blockIdx.x, cg = blockIdx.y, t = threadIdx.x;

    // ---- build f-vector in LDS ---------------------------------------------
    {
        float up = 0.f, dn = 0.f;
        #pragma unroll
        for (int m = 0; m < 16; ++m)  up += sh_in[m*H_S + t];
        #pragma unroll
        for (int m = 16; m < 32; ++m) dn += sh_in[m*H_S + t];
        fv[t]        = sh_in[n*H_S + t];
        fv[512 + t]  = up * 0.0625f;
        fv[1024 + t] = dn * 0.0625f;
        if (t < 4) {
            float s = 0.f;
            #pragma unroll
            for (int j = 0; j < 16; ++j) s += dh_in[(n*N_E + j)*4 + t];
            fv[1536 + t] = s * 0.0625f;
        } else if (t < 8) {
            int i = t - 4; float s = 0.f;
            #pragma unroll
            for (int j = 16; j < 32; ++j) s += dh_in[(n*N_E + j)*4 + i];
            fv[1540 + i] = s * 0.0625f;
        }
    }
    __syncthreads();

    // ---- stream V[li,n,:,cg*64+lane] ---------------------------------------
    int w = t >> 6, lane = t & 63;
    const float* Vb = V + ((size_t)(li*N_E + n)*F_LEN)*H_S + cg*64 + lane;
    float acc = 0.f;
    #pragma unroll 16
    for (int r = w; r < F_LEN; r += 8)
        acc = fmaf(Vb[(size_t)r * H_S], fv[r], acc);
    part[w][lane] = acc;
    __syncthreads();

    // ---- finish: 8-way column sum, tanh+bias+residual ----------------------
    if (t < 64) {
        float s = part[0][t] + part[1][t] + part[2][t] + part[3][t]
                + part[4][t] + part[5][t] + part[6][t] + part[7][t];
        int col = cg*64 + t;
        sh_out[n*H_S + col] = tanhf(s + bv[((size_t)li*N_E + n)*H_S + col])
                              + sh_in[n*H_S + col];
    }
    // ---- tiny dh update (one cg per electron) ------------------------------
    if (cg == 0 && t >= 256 && t < 384) {
        int q = t - 256, j2 = q >> 2, ii = q & 3;
        const float* Wp = Wm + ((((size_t)li*N_E + n)*N_E + j2)*4 + ii)*4;
        const float* dr = dh_in + (n*N_E + j2)*4;
        float a2 = Wp[0]*dr[0] + Wp[1]*dr[1] + Wp[2]*dr[2] + Wp[3]*dr[3];
        dh_out[(n*N_E + j2)*4 + ii] =
            tanhf(a2 + cv[(((size_t)li*N_E + n)*N_E + j2)*4 + ii]) + dr[ii];
    }
}

// ---------------------------------------------------------------------------
// Fused env + phi + 16x16 determinant. Block b: k = b>>1, spin = b&1.
__global__ __launch_bounds__(256) void k_envdet(const float* __restrict__ fw,
                                                const float* __restrict__ fb,
                                                const float* __restrict__ pw,
                                                const float* __restrict__ sw,
                                                const float* __restrict__ sh,
                                                const float* __restrict__ eNn,
                                                float* __restrict__ dets) {
    int b = blockIdx.x, k = b >> 1, sp = b & 1, base = sp * 16;
    int t = threadIdx.x;
    int i = base + (t >> 4);
    int j = base + (t & 15);

    const float* wv = fw + ((size_t)k*N_E + i)*H_S;
    const float* sv = sh + (size_t)j*H_S;
    float fd = 0.f;
    #pragma unroll 8
    for (int c = 0; c < H_S; c += 4) {
        float4 a  = *reinterpret_cast<const float4*>(wv + c);
        float4 bz = *reinterpret_cast<const float4*>(sv + c);
        fd += a.x*bz.x + a.y*bz.y + a.z*bz.z + a.w*bz.w;
    }
    fd += fb[k*N_E + i];

    const float* pv = pw + ((size_t)k*N_E + i)*N_I;
    const float* sg = sw + ((size_t)k*N_E + i)*N_I;
    const float* rn = eNn + (size_t)j*N_I;
    float env = 0.f;
    #pragma unroll 4
    for (int m = 0; m < N_I; ++m)
        env = fmaf(pv[m], expf(-fabsf(sg[m]) * rn[m]), env);

    __shared__ float phi[16][16];
    phi[t >> 4][t & 15] = fd * env;
    __syncthreads();

    if (t < 64) {
        int lane = t;
        int r = lane & 15;
        float a[16];
        #pragma unroll
        for (int c = 0; c < 16; ++c) a[c] = phi[r][c];
        bool used = (lane >= 16);
        float prod = 1.f;
        int sigma[16];
        #pragma unroll
        for (int p = 0; p < 16; ++p) {
            float v = used ? -1.f : fabsf(a[p]);
            int idx = lane;
            #pragma unroll
            for (int off = 32; off; off >>= 1) {
                float ov = __shfl_xor(v, off);
                int   oi = __shfl_xor(idx, off);
                if (ov > v || (ov == v && oi < idx)) { v = ov; idx = oi; }
            }
            int q = idx;
            float pvt = __shfl(a[p], q);
            prod *= pvt;
            sigma[p] = q;
            float factor = (!used && lane != q && pvt != 0.f) ? (a[p] / pvt) : 0.f;
            #pragma unroll
            for (int c = p; c < 16; ++c) {
                float pr = __shfl(a[c], q);
                a[c] -= factor * pr;
            }
            if (lane == q) used = true;
        }
        if (lane == 0) {
            int inv = 0;
            #pragma unroll
            for (int x = 0; x < 16; ++x)
                #pragma unroll
                for (int y = x + 1; y < 16; ++y) inv += (sigma[x] > sigma[y]) ? 1 : 0;
            dets[b] = prod * ((inv & 1) ? -1.f : 1.f);
        }
    }
}

// ---------------------------------------------------------------------------
__global__ void k_out(const float* __restrict__ dets, const float* __restrict__ omega,
                      float* __restrict__ out) {
    if (threadIdx.x == 0) {
        float s = 0.f;
        for (int k = 0; k < N_K; ++k)
            s += omega[k] * dets[2*k + 0] * dets[2*k + 1];
        out[0] = s;
    }
}

// ---------------------------------------------------------------------------
extern "C" void kernel_launch(void* const* d_in, const int* in_sizes, int n_in,
                              void* d_out, int out_size, void* d_ws, size_t ws_size,
                              hipStream_t stream) {
    const float* ep  = (const float*)d_in[0];   // [32,3]
    const float* nuc = (const float*)d_in[1];   // [128,3]
    const float* V   = (const float*)d_in[2];   // [4,32,1544,512]
    const float* bv  = (const float*)d_in[3];   // [4,32,512]
    const float* Wm  = (const float*)d_in[4];   // [4,32,32,4,4]
    const float* cv  = (const float*)d_in[5];   // [4,32,32,4]
    const float* fw  = (const float*)d_in[6];   // [16,32,512]
    const float* fb  = (const float*)d_in[7];   // [16,32]
    const float* pw  = (const float*)d_in[8];   // [16,32,128]
    const float* sw  = (const float*)d_in[9];   // [16,32,128]
    const float* om  = (const float*)d_in[10];  // [16]
    float* out = (float*)d_out;
    float* ws  = (float*)d_ws;

    float* shb[2] = { ws + WS_SH0, ws + WS_SH1 };
    float* dhb[2] = { ws + WS_DH0, ws + WS_DH1 };
    float* eNn    = ws + WS_ENN;
    float* dets   = ws + WS_DETS;

    k_init<<<dim3(1), dim3(256), 0, stream>>>(ep, nuc, ws);

    // layer sequence quirk: 0, 1, 2, then 2 again; sh/dh ping-pong
    for (int a = 0; a < 4; ++a) {
        int li = (a < 3) ? a : 2;
        k_mv<<<dim3(N_E, 8), dim3(512), 0, stream>>>(
            V, shb[a & 1], shb[(a + 1) & 1], dhb[a & 1], dhb[(a + 1) & 1],
            bv, Wm, cv, li);
    }
    // after 4 layers, final sh is in buf0
    k_envdet<<<dim3(2 * N_K), dim3(256), 0, stream>>>(
        fw, fb, pw, sw, shb[0], eNn, dets);
    k_out<<<dim3(1), dim3(64), 0, stream>>>(dets, om, out);
}